// Round 13
// baseline (183.125 us; speedup 1.0000x reference)
//
#include <hip/hip_runtime.h>
#include <hip/hip_bf16.h>

#define N_NODES 50000
#define N_EDGES 800000
#define N_GRAPHS 1024
#define D_IN 64
#define D_PROT 1280
#define HID 256
#define N_PAD 50048   // N_NODES padded to multiple of 64

// edge bucketing: 64 nodes per bucket
#define NB 782        // ceil(50048/64)
#define BCAP 2048     // capacity per bucket (mean 1023, max ~1200)
#define BEPB 2048     // edges per bucket-block (391 blocks -> 2x TLP vs 196)
#define BBLK 391      // ceil(800000/2048)

typedef __attribute__((ext_vector_type(8))) short short8;
typedef __attribute__((ext_vector_type(4))) float f32x4;
typedef __hip_bfloat16 bf16;

// round-to-nearest-even f32 -> bf16 bits (finite inputs only)
__device__ inline unsigned bf16rne(float f) {
  unsigned u = __float_as_uint(f);
  return (u + 0x7fffu + ((u >> 16) & 1u)) >> 16;
}
// accumulate 4 bf16 packed in uint2 into float4
__device__ inline void acc_bf2(float4& a, uint2 v) {
  a.x += __uint_as_float(v.x << 16);
  a.y += __uint_as_float(v.x & 0xffff0000u);
  a.z += __uint_as_float(v.y << 16);
  a.w += __uint_as_float(v.y & 0xffff0000u);
}
// accumulate 8 bf16 packed in uint4 into two float4s
__device__ inline void acc_bf4(float4& a, float4& b, uint4 v) {
  a.x += __uint_as_float(v.x << 16);
  a.y += __uint_as_float(v.x & 0xffff0000u);
  a.z += __uint_as_float(v.y << 16);
  a.w += __uint_as_float(v.y & 0xffff0000u);
  b.x += __uint_as_float(v.z << 16);
  b.y += __uint_as_float(v.z & 0xffff0000u);
  b.z += __uint_as_float(v.w << 16);
  b.w += __uint_as_float(v.w & 0xffff0000u);
}

// ---------------------------------------------------------------------------
// K1 "front": blockIdx [0,BBLK) = edge bucketing (dst register-cached between
// passes) ∪ conversions + weight packing ∪ graph-boundary precompute (gb).
// ---------------------------------------------------------------------------
#define PREP_XC 3125                  // 50000*64/4 float4s / 256
#define PREP_PE (PREP_XC + 1280)      // 1024*1280/4 / 256
#define PREP_PL (PREP_PE + 8)         // Wl: 16 coltiles * 2 kc * 64 / 256
#define PREP_PR (PREP_PL + 8)         // Wr
#define PREP_WP (PREP_PR + 160)       // Wp: 16 * 40 * 64 / 256
#define PREP_WI (PREP_WP + 64)        // Wi: 16 * 16 * 64 / 256
#define PREP_GB (PREP_WI + 196)       // gb: 50000 threads / 256

__device__ inline void pack_frag(const float* __restrict__ src, bf16* __restrict__ dst,
                                 int KC, int tid) {
  int lane = tid & 63;
  int chunk = tid >> 6;            // = c*KC + kc
  int c = chunk / KC, kc = chunk - c * KC;
  int kbase = kc * 32 + ((lane >> 4) * 8);
  int n = c * 16 + (lane & 15);
#pragma unroll
  for (int j = 0; j < 8; ++j)
    dst[(size_t)tid * 8 + j] = __float2bfloat16(src[(size_t)(kbase + j) * HID + n]);
}

__global__ __launch_bounds__(256) void k_front(
    const float* __restrict__ x, const float* __restrict__ pe,
    const float* __restrict__ Wl, const float* __restrict__ Wr,
    const float* __restrict__ Wp, const float* __restrict__ Wi,
    const int* __restrict__ ei, const int* __restrict__ batch,
    uint2* __restrict__ x2, uint2* __restrict__ pe2,
    bf16* __restrict__ Wl_pk, bf16* __restrict__ Wr_pk,
    bf16* __restrict__ Wp_pk, bf16* __restrict__ Wi_pk,
    int* __restrict__ bcnt, unsigned* __restrict__ bped,
    int* __restrict__ gb) {
  __shared__ int hist[NB];
  __shared__ int base[NB];
  const int b = blockIdx.x;
  const int t = threadIdx.x;
  if (b < BBLK) {
    const int e0 = b * BEPB;
    for (int i = t; i < NB; i += 256) hist[i] = 0;
    __syncthreads();
    // pass A: load 8 dsts into registers (kept for pass B), histogram
    int dc[8];
#pragma unroll
    for (int u = 0; u < 8; ++u) {
      int e = e0 + u * 256 + t;
      dc[u] = (e < N_EDGES) ? ei[N_EDGES + e] : -1;
    }
#pragma unroll
    for (int u = 0; u < 8; ++u)
      if (dc[u] >= 0) atomicAdd(&hist[dc[u] >> 6], 1);
    __syncthreads();
    // reservation: ONE global atomic per (block,bucket)
    for (int i = t; i < NB; i += 256) {
      int c = hist[i];
      base[i] = (c > 0) ? atomicAdd(&bcnt[i], c) : 0;
      hist[i] = 0;  // reuse as local cursor
    }
    __syncthreads();
    // pass B: load only src, scatter packed src|(local)<<16
    int sc[8];
#pragma unroll
    for (int u = 0; u < 8; ++u) {
      int e = e0 + u * 256 + t;
      sc[u] = (e < N_EDGES) ? ei[e] : 0;
    }
#pragma unroll
    for (int u = 0; u < 8; ++u) {
      int d = dc[u];
      if (d >= 0) {
        int bk = d >> 6;
        int pos = base[bk] + atomicAdd(&hist[bk], 1);
        if (pos < BCAP)
          bped[(size_t)bk * BCAP + pos] =
              (unsigned)sc[u] | ((unsigned)(d & 63) << 16);
      }
    }
    return;
  }
  const int pb = b - BBLK;
  if (pb < PREP_XC) {
    int tid = pb * 256 + t;
    float4 v = ((const float4*)x)[tid];
    x2[tid] = make_uint2(bf16rne(v.x) | (bf16rne(v.y) << 16),
                         bf16rne(v.z) | (bf16rne(v.w) << 16));
  } else if (pb < PREP_PE) {
    int tid = (pb - PREP_XC) * 256 + t;
    float4 v = ((const float4*)pe)[tid];
    pe2[tid] = make_uint2(bf16rne(v.x) | (bf16rne(v.y) << 16),
                          bf16rne(v.z) | (bf16rne(v.w) << 16));
  } else if (pb < PREP_PL) {
    pack_frag(Wl, Wl_pk, 2, (pb - PREP_PE) * 256 + t);
  } else if (pb < PREP_PR) {
    pack_frag(Wr, Wr_pk, 2, (pb - PREP_PL) * 256 + t);
  } else if (pb < PREP_WP) {
    pack_frag(Wp, Wp_pk, 40, (pb - PREP_PR) * 256 + t);
  } else if (pb < PREP_WI) {
    pack_frag(Wi, Wi_pk, 16, (pb - PREP_WP) * 256 + t);
  } else {
    // graph boundaries: gb[g] = first node index with batch >= g
    int n = (pb - PREP_WI) * 256 + t;
    if (n < N_NODES) {
      int bc = batch[n];
      int bprev = (n == 0) ? -1 : batch[n - 1];
      for (int g = bprev + 1; g <= bc; ++g) gb[g] = n;
      if (n == N_NODES - 1)
        for (int g = bc + 1; g <= N_GRAPHS; ++g) gb[g] = N_NODES;
    }
  }
}

// ---------------------------------------------------------------------------
// k_sort: one block per bucket. LDS counting-sort (s_raw staged in LDS),
// write node-sorted edge ids (esorted, contiguous -> fully merged writes)
// and per-node offsets (eoff, 65 per bucket) to global. No gather here.
// ---------------------------------------------------------------------------
__global__ __launch_bounds__(256) void k_sort(
    const unsigned* __restrict__ bped, const int* __restrict__ bcnt,
    unsigned short* __restrict__ esorted, int* __restrict__ eoff) {
  __shared__ unsigned s_raw[BCAP];     // 8 KB
  __shared__ unsigned short s_e[BCAP]; // 4 KB
  __shared__ int s_off[65];
  __shared__ int s_cur[64];
  const int t = threadIdx.x, b = blockIdx.x;
  const int nE = min(bcnt[b], BCAP);
  if (t < 64) s_cur[t] = 0;
  __syncthreads();
  for (int i = t; i < nE; i += 256) {
    unsigned pk = bped[(size_t)b * BCAP + i];
    s_raw[i] = pk;
    atomicAdd(&s_cur[(pk >> 16) & 63], 1);
  }
  __syncthreads();
  if (t < 64) {
    int sc = s_cur[t];
#pragma unroll
    for (int off = 1; off < 64; off <<= 1) {
      int u = __shfl_up(sc, off);
      if (t >= off) sc += u;
    }
    s_off[t + 1] = sc;
    if (t == 0) s_off[0] = 0;
    s_cur[t] = 0;
  }
  __syncthreads();
  for (int i = t; i < nE; i += 256) {
    unsigned pk = s_raw[i];
    int ld = (pk >> 16) & 63;
    int pos = s_off[ld] + atomicAdd(&s_cur[ld], 1);
    s_e[pos] = (unsigned short)(pk & 0xffffu);
  }
  __syncthreads();
  for (int i = t; i < nE; i += 256)
    esorted[(size_t)b * BCAP + i] = s_e[i];
  if (t < 65) eoff[b * 65 + t] = s_off[t];
}

// ---------------------------------------------------------------------------
// k_gather: 4 blocks per bucket, 16 nodes per block, 4 nodes per wave.
// No LDS, no barriers -> up to 32 waves/CU of pure latency-hiding.
// Lane layout: el=lane>>4 (edge slot), fb=lane&15 (uint2 feature block);
// 4 edges/step x 4-deep ILP = 16 row loads in flight per wave.
// ---------------------------------------------------------------------------
__global__ __launch_bounds__(256) void k_gather(
    const uint2* __restrict__ x2, const unsigned short* __restrict__ esorted,
    const int* __restrict__ eoff, uint2* __restrict__ a2) {
  const int t = threadIdx.x, w = t >> 6, lane = t & 63;
  const int el = lane >> 4, fb = lane & 15;
  const int b = blockIdx.x >> 2;
  const int nbase = (blockIdx.x & 3) * 16 + w * 4;
  const unsigned short* ep = esorted + (size_t)b * BCAP;
  const int* eo = eoff + b * 65;
#pragma unroll
  for (int k = 0; k < 4; ++k) {
    const int n = nbase + k;
    const int beg = eo[n], end = eo[n + 1];
    float4 s0 = {0,0,0,0}, s1 = {0,0,0,0}, s2 = {0,0,0,0}, s3 = {0,0,0,0};
    int e = beg;
    for (; e + 16 <= end; e += 16) {
      int i0 = ep[e + el],     i1 = ep[e + 4 + el];
      int i2 = ep[e + 8 + el], i3 = ep[e + 12 + el];
      uint2 v0 = x2[(size_t)i0 * 16 + fb];
      uint2 v1 = x2[(size_t)i1 * 16 + fb];
      uint2 v2 = x2[(size_t)i2 * 16 + fb];
      uint2 v3 = x2[(size_t)i3 * 16 + fb];
      acc_bf2(s0, v0); acc_bf2(s1, v1); acc_bf2(s2, v2); acc_bf2(s3, v3);
    }
    for (; e + 4 <= end; e += 4)
      acc_bf2(s0, x2[(size_t)ep[e + el] * 16 + fb]);
    if (e + el < end)
      acc_bf2(s1, x2[(size_t)ep[e + el] * 16 + fb]);
    float4 tt;
    tt.x = (s0.x + s1.x) + (s2.x + s3.x);
    tt.y = (s0.y + s1.y) + (s2.y + s3.y);
    tt.z = (s0.z + s1.z) + (s2.z + s3.z);
    tt.w = (s0.w + s1.w) + (s2.w + s3.w);
    tt.x += __shfl_xor(tt.x, 32); tt.x += __shfl_xor(tt.x, 16);
    tt.y += __shfl_xor(tt.y, 32); tt.y += __shfl_xor(tt.y, 16);
    tt.z += __shfl_xor(tt.z, 32); tt.z += __shfl_xor(tt.z, 16);
    tt.w += __shfl_xor(tt.w, 32); tt.w += __shfl_xor(tt.w, 16);
    const int node = b * 64 + n;
    if (el == 0 && node < N_NODES) {
      float inv = 1.0f / (float)max(end - beg, 1);
      uint2 o;
      o.x = bf16rne(tt.x * inv) | (bf16rne(tt.y * inv) << 16);
      o.y = bf16rne(tt.z * inv) | (bf16rne(tt.w * inv) << 16);
      a2[(size_t)node * 16 + fb] = o;
    }
  }
}

// ---------------------------------------------------------------------------
// k_mlp: blockIdx [0,64) = protein GEMM full-K (starts FIRST, overlaps) ->
// bf16 comb[.,256:512]+bp; blockIdx [64,64+782) = node MLP MFMA -> drug.
// ---------------------------------------------------------------------------
__global__ __launch_bounds__(256) void k_mlp(
    const bf16* __restrict__ aggrbf, const bf16* __restrict__ xbf,
    const bf16* __restrict__ Wl_pk, const bf16* __restrict__ Wr_pk,
    const float* __restrict__ bl,
    const bf16* __restrict__ pebf, const bf16* __restrict__ Wp_pk,
    const float* __restrict__ bp,
    unsigned short* __restrict__ drug, unsigned short* __restrict__ comb) {
  const int t = threadIdx.x, w = t >> 6, lane = t & 63;
  const int ml = lane & 15, q = lane >> 4;
  if (blockIdx.x < 64) {
    // protein GEMM: pe[1024x1280] @ Wp[1280x256] + bp -> comb[.,256:512]
    const int g0 = blockIdx.x * 16;
    f32x4 acc[4];
#pragma unroll
    for (int c = 0; c < 4; ++c) acc[c] = (f32x4){0.f, 0.f, 0.f, 0.f};
    for (int kc = 0; kc < 40; ++kc) {
      short8 a = *(const short8*)(pebf + (size_t)(g0 + ml) * D_PROT + kc * 32 + q * 8);
#pragma unroll
      for (int cl = 0; cl < 4; ++cl) {
        short8 bb = *(const short8*)(Wp_pk + ((size_t)((w * 4 + cl) * 40 + kc) * 64 + lane) * 8);
        acc[cl] = __builtin_amdgcn_mfma_f32_16x16x32_bf16(a, bb, acc[cl], 0, 0, 0);
      }
    }
#pragma unroll
    for (int cl = 0; cl < 4; ++cl) {
      const int col = w * 64 + cl * 16 + ml;
      const float bias = bp[col];
#pragma unroll
      for (int i = 0; i < 4; ++i)
        comb[(size_t)(g0 + q * 4 + i) * 512 + HID + col] =
            (unsigned short)bf16rne(acc[cl][i] + bias);
    }
    return;
  }
  const int n0 = (blockIdx.x - 64) * 64;
  f32x4 acc[4][4];
#pragma unroll
  for (int a = 0; a < 4; ++a)
#pragma unroll
    for (int c = 0; c < 4; ++c) acc[a][c] = (f32x4){0.f, 0.f, 0.f, 0.f};
#pragma unroll
  for (int mat = 0; mat < 2; ++mat) {
    const bf16* A = mat ? xbf : aggrbf;
    const bf16* B = mat ? Wr_pk : Wl_pk;
#pragma unroll
    for (int kc = 0; kc < 2; ++kc) {
      short8 af[4], bfr[4];
#pragma unroll
      for (int rt = 0; rt < 4; ++rt)
        af[rt] = *(const short8*)(A + (size_t)(n0 + rt * 16 + ml) * D_IN + kc * 32 + q * 8);
#pragma unroll
      for (int cl = 0; cl < 4; ++cl)
        bfr[cl] = *(const short8*)(B + ((size_t)((w * 4 + cl) * 2 + kc) * 64 + lane) * 8);
#pragma unroll
      for (int rt = 0; rt < 4; ++rt)
#pragma unroll
        for (int cl = 0; cl < 4; ++cl)
          acc[rt][cl] = __builtin_amdgcn_mfma_f32_16x16x32_bf16(af[rt], bfr[cl], acc[rt][cl], 0, 0, 0);
    }
  }
#pragma unroll
  for (int cl = 0; cl < 4; ++cl) {
    const int col = w * 64 + cl * 16 + ml;
    const float bias = bl[col];
#pragma unroll
    for (int rt = 0; rt < 4; ++rt) {
#pragma unroll
      for (int i = 0; i < 4; ++i) {
        const int row = n0 + rt * 16 + q * 4 + i;
        drug[(size_t)row * HID + col] =
            (unsigned short)bf16rne(fmaxf(acc[rt][cl][i] + bias, 0.f));
      }
    }
  }
}

// ---------------------------------------------------------------------------
// k_pool: one block per graph. uint4 loads (16 B/lane = 8 cols), 8 row-groups
// x 32 col-slices, 2-deep ILP; shfl_xor(32) pair-reduce + LDS cross-wave
// reduce; bf16 mean into comb[g][0:256]. Zero atomics.
// ---------------------------------------------------------------------------
__global__ __launch_bounds__(256) void k_pool(
    const unsigned short* __restrict__ drug, const int* __restrict__ gb,
    unsigned short* __restrict__ comb) {
  __shared__ float lds[4 * 256];   // 4 KB
  const int g = blockIdx.x, t = threadIdx.x;
  const int w = t >> 6, lane = t & 63;
  const int rg = t >> 5;           // row group 0..7
  const int cs = t & 31;           // col slice (8 cols = one uint4)
  const int lo = gb[g], hi = gb[g + 1];
  const uint4* d4 = (const uint4*)drug;
  float4 a0 = {0,0,0,0}, a1 = {0,0,0,0};
  int r = lo + rg;
  for (; r + 8 < hi; r += 16) {    // 2-deep: rows r and r+8
    uint4 v0 = d4[(size_t)r * 32 + cs];
    uint4 v1 = d4[(size_t)(r + 8) * 32 + cs];
    acc_bf4(a0, a1, v0);
    acc_bf4(a0, a1, v1);
  }
  if (r < hi) acc_bf4(a0, a1, d4[(size_t)r * 32 + cs]);
  // reduce row-group pairs within wave (lane ^ 32)
  a0.x += __shfl_xor(a0.x, 32); a0.y += __shfl_xor(a0.y, 32);
  a0.z += __shfl_xor(a0.z, 32); a0.w += __shfl_xor(a0.w, 32);
  a1.x += __shfl_xor(a1.x, 32); a1.y += __shfl_xor(a1.y, 32);
  a1.z += __shfl_xor(a1.z, 32); a1.w += __shfl_xor(a1.w, 32);
  if (lane < 32) {
    float4* dst = (float4*)(lds + w * 256 + cs * 8);
    dst[0] = a0;
    dst[1] = a1;
  }
  __syncthreads();
  float inv = 1.0f / (float)max(hi - lo, 1);
  float v = lds[0 * 256 + t] + lds[1 * 256 + t] + lds[2 * 256 + t]
          + lds[3 * 256 + t];
  comb[(size_t)g * 512 + t] = (unsigned short)bf16rne(v * inv);
}

// ---------------------------------------------------------------------------
// k_tail: MFMA interaction comb[1024x512] @ Wi_pk[512x256], then fused
// bias+relu+(*Wo)+column-reduce head. 64 blocks x 16 graphs.
// ---------------------------------------------------------------------------
__global__ __launch_bounds__(256) void k_tail(
    const bf16* __restrict__ comb, const bf16* __restrict__ Wi_pk,
    const float* __restrict__ bi, const float* __restrict__ Wo,
    const float* __restrict__ bo, float* __restrict__ out) {
  __shared__ float sRed[16 * 4];
  const int t = threadIdx.x, w = t >> 6, lane = t & 63;
  const int ml = lane & 15, q = lane >> 4;
  const int g0 = blockIdx.x * 16;
  f32x4 acc[4];
#pragma unroll
  for (int c = 0; c < 4; ++c) acc[c] = (f32x4){0.f, 0.f, 0.f, 0.f};
  for (int kc = 0; kc < 16; ++kc) {
    short8 a = *(const short8*)(comb + (size_t)(g0 + ml) * 512 + kc * 32 + q * 8);
#pragma unroll
    for (int cl = 0; cl < 4; ++cl) {
      short8 bb = *(const short8*)(Wi_pk + ((size_t)((w * 4 + cl) * 16 + kc) * 64 + lane) * 8);
      acc[cl] = __builtin_amdgcn_mfma_f32_16x16x32_bf16(a, bb, acc[cl], 0, 0, 0);
    }
  }
  float bic[4], woc[4];
#pragma unroll
  for (int cl = 0; cl < 4; ++cl) {
    const int col = w * 64 + cl * 16 + ml;
    bic[cl] = bi[col];
    woc[cl] = Wo[col];
  }
#pragma unroll
  for (int i = 0; i < 4; ++i) {
    float s = 0.f;
#pragma unroll
    for (int cl = 0; cl < 4; ++cl)
      s += fmaxf(acc[cl][i] + bic[cl], 0.f) * woc[cl];
    s += __shfl_xor(s, 1); s += __shfl_xor(s, 2);
    s += __shfl_xor(s, 4); s += __shfl_xor(s, 8);
    if (ml == 0) sRed[(q * 4 + i) * 4 + w] = s;
  }
  __syncthreads();
  if (t < 16)
    out[g0 + t] = sRed[t * 4 + 0] + sRed[t * 4 + 1] + sRed[t * 4 + 2]
                + sRed[t * 4 + 3] + bo[0];
}

extern "C" void kernel_launch(void* const* d_in, const int* in_sizes, int n_in,
                              void* d_out, int out_size, void* d_ws, size_t ws_size,
                              hipStream_t stream) {
  const float* x     = (const float*)d_in[0];
  const float* pe    = (const float*)d_in[1];
  const float* Wl    = (const float*)d_in[2];
  const float* bl    = (const float*)d_in[3];
  const float* Wr    = (const float*)d_in[4];
  const float* Wp    = (const float*)d_in[5];
  const float* bp    = (const float*)d_in[6];
  const float* Wi    = (const float*)d_in[7];
  const float* bi    = (const float*)d_in[8];
  const float* Wo    = (const float*)d_in[9];
  const float* bo    = (const float*)d_in[10];
  const int*   ei    = (const int*)d_in[11];
  const int*   batch = (const int*)d_in[12];
  float* out = (float*)d_out;

  char* p = (char*)d_ws;
  auto alloc = [&](size_t bytes) {
    char* r = p;
    p += (bytes + 255) & ~(size_t)255;
    return r;
  };
  int*      bcnt  = (int*)alloc(NB * 4);
  size_t zbytes = (size_t)(p - (char*)d_ws);     // only bcnt needs zeroing
  unsigned* bped  = (unsigned*)alloc((size_t)NB * BCAP * 4);
  unsigned short* esorted = (unsigned short*)alloc((size_t)NB * BCAP * 2);
  int*   eoff   = (int*)alloc((size_t)NB * 65 * 4);
  bf16*  xbf    = (bf16*)alloc((size_t)N_PAD * D_IN * 2);
  bf16*  aggrbf = (bf16*)alloc((size_t)N_PAD * D_IN * 2);
  bf16*  pebf   = (bf16*)alloc((size_t)N_GRAPHS * D_PROT * 2);
  bf16*  Wl_pk  = (bf16*)alloc((size_t)D_IN * HID * 2);
  bf16*  Wr_pk  = (bf16*)alloc((size_t)D_IN * HID * 2);
  bf16*  Wp_pk  = (bf16*)alloc((size_t)D_PROT * HID * 2);
  bf16*  Wi_pk  = (bf16*)alloc((size_t)2 * HID * HID * 2);
  int*   gb     = (int*)alloc((N_GRAPHS + 1) * 4);
  unsigned short* drug = (unsigned short*)alloc((size_t)N_PAD * HID * 2);
  unsigned short* comb = (unsigned short*)alloc((size_t)N_GRAPHS * 2 * HID * 2);

  (void)hipMemsetAsync(d_ws, 0, zbytes, stream);

  k_front<<<BBLK + PREP_GB, 256, 0, stream>>>(
      x, pe, Wl, Wr, Wp, Wi, ei, batch,
      (uint2*)xbf, (uint2*)pebf, Wl_pk, Wr_pk, Wp_pk, Wi_pk, bcnt, bped, gb);
  k_sort<<<NB, 256, 0, stream>>>(bped, bcnt, esorted, eoff);
  k_gather<<<NB * 4, 256, 0, stream>>>(
      (const uint2*)xbf, esorted, eoff, (uint2*)aggrbf);
  k_mlp<<<64 + NB, 256, 0, stream>>>(
      aggrbf, xbf, Wl_pk, Wr_pk, bl, pebf, Wp_pk, bp, drug, comb);
  k_pool<<<N_GRAPHS, 256, 0, stream>>>(drug, gb, comb);
  k_tail<<<N_GRAPHS / 16, 256, 0, stream>>>((const bf16*)comb, Wi_pk, bi, Wo, bo, out);
}

// Round 14
// 176.953 us; speedup vs baseline: 1.0349x; 1.0349x over previous
//
#include <hip/hip_runtime.h>
#include <hip/hip_bf16.h>

#define N_NODES 50000
#define N_EDGES 800000
#define N_GRAPHS 1024
#define D_IN 64
#define D_PROT 1280
#define HID 256
#define N_PAD 50048   // N_NODES padded to multiple of 64

// edge bucketing: 64 nodes per bucket
#define NB 782        // ceil(50048/64)
#define BCAP 2048     // capacity per bucket (mean 1023, max ~1200)
#define BEPB 4096     // edges per bucket-block (196 blocks: long runs -> merged writes)
#define BBLK 196      // ceil(800000/4096)

typedef __attribute__((ext_vector_type(8))) short short8;
typedef __attribute__((ext_vector_type(4))) float f32x4;
typedef __hip_bfloat16 bf16;

// round-to-nearest-even f32 -> bf16 bits (finite inputs only)
__device__ inline unsigned bf16rne(float f) {
  unsigned u = __float_as_uint(f);
  return (u + 0x7fffu + ((u >> 16) & 1u)) >> 16;
}
// accumulate 4 bf16 packed in uint2 into float4
__device__ inline void acc_bf2(float4& a, uint2 v) {
  a.x += __uint_as_float(v.x << 16);
  a.y += __uint_as_float(v.x & 0xffff0000u);
  a.z += __uint_as_float(v.y << 16);
  a.w += __uint_as_float(v.y & 0xffff0000u);
}
// accumulate 8 bf16 packed in uint4 into two float4s
__device__ inline void acc_bf4(float4& a, float4& b, uint4 v) {
  a.x += __uint_as_float(v.x << 16);
  a.y += __uint_as_float(v.x & 0xffff0000u);
  a.z += __uint_as_float(v.y << 16);
  a.w += __uint_as_float(v.y & 0xffff0000u);
  b.x += __uint_as_float(v.z << 16);
  b.y += __uint_as_float(v.z & 0xffff0000u);
  b.z += __uint_as_float(v.w << 16);
  b.w += __uint_as_float(v.w & 0xffff0000u);
}

// ---------------------------------------------------------------------------
// K1 "front": blockIdx [0,BBLK) = edge bucketing (dst register-cached between
// passes, 16 edges/thread) ∪ conversions + weight packing ∪ gb precompute.
// ---------------------------------------------------------------------------
#define PREP_XC 3125                  // 50000*64/4 float4s / 256
#define PREP_PE (PREP_XC + 1280)      // 1024*1280/4 / 256
#define PREP_PL (PREP_PE + 8)         // Wl: 16 coltiles * 2 kc * 64 / 256
#define PREP_PR (PREP_PL + 8)         // Wr
#define PREP_WP (PREP_PR + 160)       // Wp: 16 * 40 * 64 / 256
#define PREP_WI (PREP_WP + 64)        // Wi: 16 * 16 * 64 / 256
#define PREP_GB (PREP_WI + 196)       // gb: 50000 threads / 256

__device__ inline void pack_frag(const float* __restrict__ src, bf16* __restrict__ dst,
                                 int KC, int tid) {
  int lane = tid & 63;
  int chunk = tid >> 6;            // = c*KC + kc
  int c = chunk / KC, kc = chunk - c * KC;
  int kbase = kc * 32 + ((lane >> 4) * 8);
  int n = c * 16 + (lane & 15);
#pragma unroll
  for (int j = 0; j < 8; ++j)
    dst[(size_t)tid * 8 + j] = __float2bfloat16(src[(size_t)(kbase + j) * HID + n]);
}

__global__ __launch_bounds__(256) void k_front(
    const float* __restrict__ x, const float* __restrict__ pe,
    const float* __restrict__ Wl, const float* __restrict__ Wr,
    const float* __restrict__ Wp, const float* __restrict__ Wi,
    const int* __restrict__ ei, const int* __restrict__ batch,
    uint2* __restrict__ x2, uint2* __restrict__ pe2,
    bf16* __restrict__ Wl_pk, bf16* __restrict__ Wr_pk,
    bf16* __restrict__ Wp_pk, bf16* __restrict__ Wi_pk,
    int* __restrict__ bcnt, unsigned* __restrict__ bped,
    int* __restrict__ gb) {
  __shared__ int hist[NB];
  __shared__ int base[NB];
  const int b = blockIdx.x;
  const int t = threadIdx.x;
  if (b < BBLK) {
    const int e0 = b * BEPB;
    for (int i = t; i < NB; i += 256) hist[i] = 0;
    __syncthreads();
    // pass A: load 16 dsts into registers (kept for pass B), histogram
    int dc[16];
#pragma unroll
    for (int o = 0; o < 4; ++o)
#pragma unroll
      for (int u = 0; u < 4; ++u) {
        int e = e0 + o * 1024 + u * 256 + t;
        dc[o * 4 + u] = (e < N_EDGES) ? ei[N_EDGES + e] : -1;
      }
#pragma unroll
    for (int j = 0; j < 16; ++j)
      if (dc[j] >= 0) atomicAdd(&hist[dc[j] >> 6], 1);
    __syncthreads();
    // reservation: ONE global atomic per (block,bucket)
    for (int i = t; i < NB; i += 256) {
      int c = hist[i];
      base[i] = (c > 0) ? atomicAdd(&bcnt[i], c) : 0;
      hist[i] = 0;  // reuse as local cursor
    }
    __syncthreads();
    // pass B: load only src, scatter packed src|(local)<<16
#pragma unroll
    for (int o = 0; o < 4; ++o) {
      int sc[4];
#pragma unroll
      for (int u = 0; u < 4; ++u) {
        int e = e0 + o * 1024 + u * 256 + t;
        sc[u] = (e < N_EDGES) ? ei[e] : 0;
      }
#pragma unroll
      for (int u = 0; u < 4; ++u) {
        int d = dc[o * 4 + u];
        if (d >= 0) {
          int bk = d >> 6;
          int pos = base[bk] + atomicAdd(&hist[bk], 1);
          if (pos < BCAP)
            bped[(size_t)bk * BCAP + pos] =
                (unsigned)sc[u] | ((unsigned)(d & 63) << 16);
        }
      }
    }
    return;
  }
  const int pb = b - BBLK;
  if (pb < PREP_XC) {
    int tid = pb * 256 + t;
    float4 v = ((const float4*)x)[tid];
    x2[tid] = make_uint2(bf16rne(v.x) | (bf16rne(v.y) << 16),
                         bf16rne(v.z) | (bf16rne(v.w) << 16));
  } else if (pb < PREP_PE) {
    int tid = (pb - PREP_XC) * 256 + t;
    float4 v = ((const float4*)pe)[tid];
    pe2[tid] = make_uint2(bf16rne(v.x) | (bf16rne(v.y) << 16),
                          bf16rne(v.z) | (bf16rne(v.w) << 16));
  } else if (pb < PREP_PL) {
    pack_frag(Wl, Wl_pk, 2, (pb - PREP_PE) * 256 + t);
  } else if (pb < PREP_PR) {
    pack_frag(Wr, Wr_pk, 2, (pb - PREP_PL) * 256 + t);
  } else if (pb < PREP_WP) {
    pack_frag(Wp, Wp_pk, 40, (pb - PREP_PR) * 256 + t);
  } else if (pb < PREP_WI) {
    pack_frag(Wi, Wi_pk, 16, (pb - PREP_WP) * 256 + t);
  } else {
    // graph boundaries: gb[g] = first node index with batch >= g
    int n = (pb - PREP_WI) * 256 + t;
    if (n < N_NODES) {
      int bc = batch[n];
      int bprev = (n == 0) ? -1 : batch[n - 1];
      for (int g = bprev + 1; g <= bc; ++g) gb[g] = n;
      if (n == N_NODES - 1)
        for (int g = bc + 1; g <= N_GRAPHS; ++g) gb[g] = N_NODES;
    }
  }
}

// ---------------------------------------------------------------------------
// k_sort: one block per bucket. LDS counting-sort (s_raw staged in LDS),
// write node-sorted edge ids (esorted, contiguous -> fully merged writes)
// and per-node offsets (eoff, 65 per bucket) to global. No gather here.
// ---------------------------------------------------------------------------
__global__ __launch_bounds__(256) void k_sort(
    const unsigned* __restrict__ bped, const int* __restrict__ bcnt,
    unsigned short* __restrict__ esorted, int* __restrict__ eoff) {
  __shared__ unsigned s_raw[BCAP];     // 8 KB
  __shared__ unsigned short s_e[BCAP]; // 4 KB
  __shared__ int s_off[65];
  __shared__ int s_cur[64];
  const int t = threadIdx.x, b = blockIdx.x;
  const int nE = min(bcnt[b], BCAP);
  if (t < 64) s_cur[t] = 0;
  __syncthreads();
  for (int i = t; i < nE; i += 256) {
    unsigned pk = bped[(size_t)b * BCAP + i];
    s_raw[i] = pk;
    atomicAdd(&s_cur[(pk >> 16) & 63], 1);
  }
  __syncthreads();
  if (t < 64) {
    int sc = s_cur[t];
#pragma unroll
    for (int off = 1; off < 64; off <<= 1) {
      int u = __shfl_up(sc, off);
      if (t >= off) sc += u;
    }
    s_off[t + 1] = sc;
    if (t == 0) s_off[0] = 0;
    s_cur[t] = 0;
  }
  __syncthreads();
  for (int i = t; i < nE; i += 256) {
    unsigned pk = s_raw[i];
    int ld = (pk >> 16) & 63;
    int pos = s_off[ld] + atomicAdd(&s_cur[ld], 1);
    s_e[pos] = (unsigned short)(pk & 0xffffu);
  }
  __syncthreads();
  for (int i = t; i < nE; i += 256)
    esorted[(size_t)b * BCAP + i] = s_e[i];
  if (t < 65) eoff[b * 65 + t] = s_off[t];
}

// ---------------------------------------------------------------------------
// k_gather: 4 blocks per bucket, 16 nodes per block, 4 nodes per wave.
// No LDS, no barriers -> up to 32 waves/CU of pure latency-hiding.
// Lane layout: el=lane>>4 (edge slot), fb=lane&15 (uint2 feature block);
// 4 edges/step x 4-deep ILP = 16 row loads in flight per wave.
// ---------------------------------------------------------------------------
__global__ __launch_bounds__(256) void k_gather(
    const uint2* __restrict__ x2, const unsigned short* __restrict__ esorted,
    const int* __restrict__ eoff, uint2* __restrict__ a2) {
  const int t = threadIdx.x, w = t >> 6, lane = t & 63;
  const int el = lane >> 4, fb = lane & 15;
  const int b = blockIdx.x >> 2;
  const int nbase = (blockIdx.x & 3) * 16 + w * 4;
  const unsigned short* ep = esorted + (size_t)b * BCAP;
  const int* eo = eoff + b * 65;
#pragma unroll
  for (int k = 0; k < 4; ++k) {
    const int n = nbase + k;
    const int beg = eo[n], end = eo[n + 1];
    float4 s0 = {0,0,0,0}, s1 = {0,0,0,0}, s2 = {0,0,0,0}, s3 = {0,0,0,0};
    int e = beg;
    for (; e + 16 <= end; e += 16) {
      int i0 = ep[e + el],     i1 = ep[e + 4 + el];
      int i2 = ep[e + 8 + el], i3 = ep[e + 12 + el];
      uint2 v0 = x2[(size_t)i0 * 16 + fb];
      uint2 v1 = x2[(size_t)i1 * 16 + fb];
      uint2 v2 = x2[(size_t)i2 * 16 + fb];
      uint2 v3 = x2[(size_t)i3 * 16 + fb];
      acc_bf2(s0, v0); acc_bf2(s1, v1); acc_bf2(s2, v2); acc_bf2(s3, v3);
    }
    for (; e + 4 <= end; e += 4)
      acc_bf2(s0, x2[(size_t)ep[e + el] * 16 + fb]);
    if (e + el < end)
      acc_bf2(s1, x2[(size_t)ep[e + el] * 16 + fb]);
    float4 tt;
    tt.x = (s0.x + s1.x) + (s2.x + s3.x);
    tt.y = (s0.y + s1.y) + (s2.y + s3.y);
    tt.z = (s0.z + s1.z) + (s2.z + s3.z);
    tt.w = (s0.w + s1.w) + (s2.w + s3.w);
    tt.x += __shfl_xor(tt.x, 32); tt.x += __shfl_xor(tt.x, 16);
    tt.y += __shfl_xor(tt.y, 32); tt.y += __shfl_xor(tt.y, 16);
    tt.z += __shfl_xor(tt.z, 32); tt.z += __shfl_xor(tt.z, 16);
    tt.w += __shfl_xor(tt.w, 32); tt.w += __shfl_xor(tt.w, 16);
    const int node = b * 64 + n;
    if (el == 0 && node < N_NODES) {
      float inv = 1.0f / (float)max(end - beg, 1);
      uint2 o;
      o.x = bf16rne(tt.x * inv) | (bf16rne(tt.y * inv) << 16);
      o.y = bf16rne(tt.z * inv) | (bf16rne(tt.w * inv) << 16);
      a2[(size_t)node * 16 + fb] = o;
    }
  }
}

// ---------------------------------------------------------------------------
// k_mlp: blockIdx [0,64) = protein GEMM full-K (starts FIRST, overlaps) ->
// bf16 comb[.,256:512]+bp; blockIdx [64,64+782) = node MLP MFMA -> drug.
// ---------------------------------------------------------------------------
__global__ __launch_bounds__(256) void k_mlp(
    const bf16* __restrict__ aggrbf, const bf16* __restrict__ xbf,
    const bf16* __restrict__ Wl_pk, const bf16* __restrict__ Wr_pk,
    const float* __restrict__ bl,
    const bf16* __restrict__ pebf, const bf16* __restrict__ Wp_pk,
    const float* __restrict__ bp,
    unsigned short* __restrict__ drug, unsigned short* __restrict__ comb) {
  const int t = threadIdx.x, w = t >> 6, lane = t & 63;
  const int ml = lane & 15, q = lane >> 4;
  if (blockIdx.x < 64) {
    // protein GEMM: pe[1024x1280] @ Wp[1280x256] + bp -> comb[.,256:512]
    const int g0 = blockIdx.x * 16;
    f32x4 acc[4];
#pragma unroll
    for (int c = 0; c < 4; ++c) acc[c] = (f32x4){0.f, 0.f, 0.f, 0.f};
    for (int kc = 0; kc < 40; ++kc) {
      short8 a = *(const short8*)(pebf + (size_t)(g0 + ml) * D_PROT + kc * 32 + q * 8);
#pragma unroll
      for (int cl = 0; cl < 4; ++cl) {
        short8 bb = *(const short8*)(Wp_pk + ((size_t)((w * 4 + cl) * 40 + kc) * 64 + lane) * 8);
        acc[cl] = __builtin_amdgcn_mfma_f32_16x16x32_bf16(a, bb, acc[cl], 0, 0, 0);
      }
    }
#pragma unroll
    for (int cl = 0; cl < 4; ++cl) {
      const int col = w * 64 + cl * 16 + ml;
      const float bias = bp[col];
#pragma unroll
      for (int i = 0; i < 4; ++i)
        comb[(size_t)(g0 + q * 4 + i) * 512 + HID + col] =
            (unsigned short)bf16rne(acc[cl][i] + bias);
    }
    return;
  }
  const int n0 = (blockIdx.x - 64) * 64;
  f32x4 acc[4][4];
#pragma unroll
  for (int a = 0; a < 4; ++a)
#pragma unroll
    for (int c = 0; c < 4; ++c) acc[a][c] = (f32x4){0.f, 0.f, 0.f, 0.f};
#pragma unroll
  for (int mat = 0; mat < 2; ++mat) {
    const bf16* A = mat ? xbf : aggrbf;
    const bf16* B = mat ? Wr_pk : Wl_pk;
#pragma unroll
    for (int kc = 0; kc < 2; ++kc) {
      short8 af[4], bfr[4];
#pragma unroll
      for (int rt = 0; rt < 4; ++rt)
        af[rt] = *(const short8*)(A + (size_t)(n0 + rt * 16 + ml) * D_IN + kc * 32 + q * 8);
#pragma unroll
      for (int cl = 0; cl < 4; ++cl)
        bfr[cl] = *(const short8*)(B + ((size_t)((w * 4 + cl) * 2 + kc) * 64 + lane) * 8);
#pragma unroll
      for (int rt = 0; rt < 4; ++rt)
#pragma unroll
        for (int cl = 0; cl < 4; ++cl)
          acc[rt][cl] = __builtin_amdgcn_mfma_f32_16x16x32_bf16(af[rt], bfr[cl], acc[rt][cl], 0, 0, 0);
    }
  }
#pragma unroll
  for (int cl = 0; cl < 4; ++cl) {
    const int col = w * 64 + cl * 16 + ml;
    const float bias = bl[col];
#pragma unroll
    for (int rt = 0; rt < 4; ++rt) {
#pragma unroll
      for (int i = 0; i < 4; ++i) {
        const int row = n0 + rt * 16 + q * 4 + i;
        drug[(size_t)row * HID + col] =
            (unsigned short)bf16rne(fmaxf(acc[rt][cl][i] + bias, 0.f));
      }
    }
  }
}

// ---------------------------------------------------------------------------
// k_pool: one block per graph. uint4 loads (16 B/lane = 8 cols), 8 row-groups
// x 32 col-slices, 2-deep ILP; shfl_xor(32) pair-reduce + LDS cross-wave
// reduce; bf16 mean into comb[g][0:256]. Zero atomics.
// ---------------------------------------------------------------------------
__global__ __launch_bounds__(256) void k_pool(
    const unsigned short* __restrict__ drug, const int* __restrict__ gb,
    unsigned short* __restrict__ comb) {
  __shared__ float lds[4 * 256];   // 4 KB
  const int g = blockIdx.x, t = threadIdx.x;
  const int w = t >> 6, lane = t & 63;
  const int rg = t >> 5;           // row group 0..7
  const int cs = t & 31;           // col slice (8 cols = one uint4)
  const int lo = gb[g], hi = gb[g + 1];
  const uint4* d4 = (const uint4*)drug;
  float4 a0 = {0,0,0,0}, a1 = {0,0,0,0};
  int r = lo + rg;
  for (; r + 8 < hi; r += 16) {    // 2-deep: rows r and r+8
    uint4 v0 = d4[(size_t)r * 32 + cs];
    uint4 v1 = d4[(size_t)(r + 8) * 32 + cs];
    acc_bf4(a0, a1, v0);
    acc_bf4(a0, a1, v1);
  }
  if (r < hi) acc_bf4(a0, a1, d4[(size_t)r * 32 + cs]);
  // reduce row-group pairs within wave (lane ^ 32)
  a0.x += __shfl_xor(a0.x, 32); a0.y += __shfl_xor(a0.y, 32);
  a0.z += __shfl_xor(a0.z, 32); a0.w += __shfl_xor(a0.w, 32);
  a1.x += __shfl_xor(a1.x, 32); a1.y += __shfl_xor(a1.y, 32);
  a1.z += __shfl_xor(a1.z, 32); a1.w += __shfl_xor(a1.w, 32);
  if (lane < 32) {
    float4* dst = (float4*)(lds + w * 256 + cs * 8);
    dst[0] = a0;
    dst[1] = a1;
  }
  __syncthreads();
  float inv = 1.0f / (float)max(hi - lo, 1);
  float v = lds[0 * 256 + t] + lds[1 * 256 + t] + lds[2 * 256 + t]
          + lds[3 * 256 + t];
  comb[(size_t)g * 512 + t] = (unsigned short)bf16rne(v * inv);
}

// ---------------------------------------------------------------------------
// k_tail: MFMA interaction comb[1024x512] @ Wi_pk[512x256], then fused
// bias+relu+(*Wo)+column-reduce head. 64 blocks x 16 graphs.
// ---------------------------------------------------------------------------
__global__ __launch_bounds__(256) void k_tail(
    const bf16* __restrict__ comb, const bf16* __restrict__ Wi_pk,
    const float* __restrict__ bi, const float* __restrict__ Wo,
    const float* __restrict__ bo, float* __restrict__ out) {
  __shared__ float sRed[16 * 4];
  const int t = threadIdx.x, w = t >> 6, lane = t & 63;
  const int ml = lane & 15, q = lane >> 4;
  const int g0 = blockIdx.x * 16;
  f32x4 acc[4];
#pragma unroll
  for (int c = 0; c < 4; ++c) acc[c] = (f32x4){0.f, 0.f, 0.f, 0.f};
  for (int kc = 0; kc < 16; ++kc) {
    short8 a = *(const short8*)(comb + (size_t)(g0 + ml) * 512 + kc * 32 + q * 8);
#pragma unroll
    for (int cl = 0; cl < 4; ++cl) {
      short8 bb = *(const short8*)(Wi_pk + ((size_t)((w * 4 + cl) * 16 + kc) * 64 + lane) * 8);
      acc[cl] = __builtin_amdgcn_mfma_f32_16x16x32_bf16(a, bb, acc[cl], 0, 0, 0);
    }
  }
  float bic[4], woc[4];
#pragma unroll
  for (int cl = 0; cl < 4; ++cl) {
    const int col = w * 64 + cl * 16 + ml;
    bic[cl] = bi[col];
    woc[cl] = Wo[col];
  }
#pragma unroll
  for (int i = 0; i < 4; ++i) {
    float s = 0.f;
#pragma unroll
    for (int cl = 0; cl < 4; ++cl)
      s += fmaxf(acc[cl][i] + bic[cl], 0.f) * woc[cl];
    s += __shfl_xor(s, 1); s += __shfl_xor(s, 2);
    s += __shfl_xor(s, 4); s += __shfl_xor(s, 8);
    if (ml == 0) sRed[(q * 4 + i) * 4 + w] = s;
  }
  __syncthreads();
  if (t < 16)
    out[g0 + t] = sRed[t * 4 + 0] + sRed[t * 4 + 1] + sRed[t * 4 + 2]
                + sRed[t * 4 + 3] + bo[0];
}

extern "C" void kernel_launch(void* const* d_in, const int* in_sizes, int n_in,
                              void* d_out, int out_size, void* d_ws, size_t ws_size,
                              hipStream_t stream) {
  const float* x     = (const float*)d_in[0];
  const float* pe    = (const float*)d_in[1];
  const float* Wl    = (const float*)d_in[2];
  const float* bl    = (const float*)d_in[3];
  const float* Wr    = (const float*)d_in[4];
  const float* Wp    = (const float*)d_in[5];
  const float* bp    = (const float*)d_in[6];
  const float* Wi    = (const float*)d_in[7];
  const float* bi    = (const float*)d_in[8];
  const float* Wo    = (const float*)d_in[9];
  const float* bo    = (const float*)d_in[10];
  const int*   ei    = (const int*)d_in[11];
  const int*   batch = (const int*)d_in[12];
  float* out = (float*)d_out;

  char* p = (char*)d_ws;
  auto alloc = [&](size_t bytes) {
    char* r = p;
    p += (bytes + 255) & ~(size_t)255;
    return r;
  };
  int*      bcnt  = (int*)alloc(NB * 4);
  size_t zbytes = (size_t)(p - (char*)d_ws);     // only bcnt needs zeroing
  unsigned* bped  = (unsigned*)alloc((size_t)NB * BCAP * 4);
  unsigned short* esorted = (unsigned short*)alloc((size_t)NB * BCAP * 2);
  int*   eoff   = (int*)alloc((size_t)NB * 65 * 4);
  bf16*  xbf    = (bf16*)alloc((size_t)N_PAD * D_IN * 2);
  bf16*  aggrbf = (bf16*)alloc((size_t)N_PAD * D_IN * 2);
  bf16*  pebf   = (bf16*)alloc((size_t)N_GRAPHS * D_PROT * 2);
  bf16*  Wl_pk  = (bf16*)alloc((size_t)D_IN * HID * 2);
  bf16*  Wr_pk  = (bf16*)alloc((size_t)D_IN * HID * 2);
  bf16*  Wp_pk  = (bf16*)alloc((size_t)D_PROT * HID * 2);
  bf16*  Wi_pk  = (bf16*)alloc((size_t)2 * HID * HID * 2);
  int*   gb     = (int*)alloc((N_GRAPHS + 1) * 4);
  unsigned short* drug = (unsigned short*)alloc((size_t)N_PAD * HID * 2);
  unsigned short* comb = (unsigned short*)alloc((size_t)N_GRAPHS * 2 * HID * 2);

  (void)hipMemsetAsync(d_ws, 0, zbytes, stream);

  k_front<<<BBLK + PREP_GB, 256, 0, stream>>>(
      x, pe, Wl, Wr, Wp, Wi, ei, batch,
      (uint2*)xbf, (uint2*)pebf, Wl_pk, Wr_pk, Wp_pk, Wi_pk, bcnt, bped, gb);
  k_sort<<<NB, 256, 0, stream>>>(bped, bcnt, esorted, eoff);
  k_gather<<<NB * 4, 256, 0, stream>>>(
      (const uint2*)xbf, esorted, eoff, (uint2*)aggrbf);
  k_mlp<<<64 + NB, 256, 0, stream>>>(
      aggrbf, xbf, Wl_pk, Wr_pk, bl, pebf, Wp_pk, bp, drug, comb);
  k_pool<<<N_GRAPHS, 256, 0, stream>>>(drug, gb, comb);
  k_tail<<<N_GRAPHS / 16, 256, 0, stream>>>((const bf16*)comb, Wi_pk, bi, Wo, bo, out);
}